// Round 25
// baseline (47.696 us; speedup 1.0000x reference)
//
#include <hip/hip_runtime.h>
#include <hip/hip_bf16.h>

typedef __attribute__((ext_vector_type(8))) short bf16x8;
typedef __attribute__((ext_vector_type(4))) float f32x4;

#define BATCH 16
#define SEQ   1024
#define EMB   768
#define HEAD  64
#define NT    (BATCH*SEQ)
#define NQKV  192
#define OSTR  200        // epilogue LDS tile stride (ushorts)

__device__ inline ushort f2bf(float f) {
  __hip_bfloat16 h = __float2bfloat16(f);
  return *reinterpret_cast<const ushort*>(&h);
}

__device__ inline void lds_dma16(const void* g, void* l) {
  __builtin_amdgcn_global_load_lds(
      (const __attribute__((address_space(1))) void*)g,
      (__attribute__((address_space(3))) void*)l, 16, 0, 0);
}

// ---------- W fp32 -> wt bf16 (pre-swizzled rows: chunk g stored at g^(row&7)) ----------
__global__ __launch_bounds__(256) void convw_kernel(
    const float* __restrict__ Wq, const float* __restrict__ Wk,
    const float* __restrict__ Wv, ushort* __restrict__ wt)
{
  const int row = blockIdx.x * 8 + (threadIdx.x >> 5);
  const float* W = (row < 64) ? Wq : (row < 128 ? Wk : Wv);
  const int r = row & 63;
  #pragma unroll
  for (int j = 0; j < 3; ++j) {
    const int c = (threadIdx.x & 31) + 32 * j;   // stored chunk 0..95
    const int grp = c >> 3, gst = c & 7;
    const int glog = gst ^ (row & 7);
    const int srccol = (grp << 6) + (glog << 3);
    const float4 f0 = *reinterpret_cast<const float4*>(&W[(size_t)r * EMB + srccol]);
    const float4 f1 = *reinterpret_cast<const float4*>(&W[(size_t)r * EMB + srccol + 4]);
    union { ushort us[8]; uint4 u; } o;
    o.us[0]=f2bf(f0.x); o.us[1]=f2bf(f0.y); o.us[2]=f2bf(f0.z); o.us[3]=f2bf(f0.w);
    o.us[4]=f2bf(f1.x); o.us[5]=f2bf(f1.y); o.us[6]=f2bf(f1.z); o.us[7]=f2bf(f1.w);
    *reinterpret_cast<uint4*>(&wt[(size_t)row * EMB + (c << 3)]) = o.u;
  }
}

// ---------- proj v5c: R15 body, W SINGLE-buffered -> 40 KB LDS -> 4 blocks/CU ----------
// grid 256 x 512 thr (8 waves). Block: M=64, N=192, BK=64. 2 barriers/phase;
// co-residency (32 waves/CU) hides the per-block W-DMA window.
__global__ __launch_bounds__(512, 8) void proj_kernel(
    const float* __restrict__ x, const ushort* __restrict__ wt,
    ushort* __restrict__ qo, ushort* __restrict__ ko, ushort* __restrict__ vo)
{
  __shared__ ushort SM[20480];   // 40 KB: X 2x8KB | W 24KB single; epilogue reuses as [64][OSTR]

  const int tid  = threadIdx.x;
  const int wave = tid >> 6, lane = tid & 63;
  const int m0   = blockIdx.x * 64;
  const int wr   = wave >> 2, wc = wave & 3;
  const int col16 = lane & 15, quad = lane >> 4;

  const int xrow = tid >> 3;             // 0..63
  const int xc   = (tid & 7) * 8;        // float col
  const int xchk = tid & 7;              // 16B chunk idx

  float4 xa, xb;

  #define XL(buf_, idx_) SM[(buf_) * 4096 + (idx_)]
  #define WL(idx_)       SM[8192 + (idx_)]

  #define LOADX(kt_) {                                                          \
    xa = *reinterpret_cast<const float4*>(&x[(size_t)(m0 + xrow) * EMB + (kt_) * 64 + xc]);     \
    xb = *reinterpret_cast<const float4*>(&x[(size_t)(m0 + xrow) * EMB + (kt_) * 64 + xc + 4]); }

  #define WRITEX(buf_) {                                                        \
    union { ushort us[8]; uint4 u; } p;                                         \
    p.us[0]=f2bf(xa.x); p.us[1]=f2bf(xa.y); p.us[2]=f2bf(xa.z); p.us[3]=f2bf(xa.w); \
    p.us[4]=f2bf(xb.x); p.us[5]=f2bf(xb.y); p.us[6]=f2bf(xb.z); p.us[7]=f2bf(xb.w); \
    *reinterpret_cast<uint4*>(&XL(buf_, xrow * 64 + ((xchk ^ (xrow & 7)) << 3))) = p.u; }

  #define STAGEW(kt_) { _Pragma("unroll")                                       \
    for (int u = 0; u < 3; ++u) {                                               \
      lds_dma16(&wt[(size_t)(u * 64 + (tid >> 3)) * EMB + (kt_) * 64 + (tid & 7) * 8], \
                &WL((u * 64 + wave * 8) * 64));                                 \
    } }

  f32x4 acc[2][3];
  #pragma unroll
  for (int m = 0; m < 2; ++m)
    #pragma unroll
    for (int n = 0; n < 3; ++n) acc[m][n] = (f32x4){0.f, 0.f, 0.f, 0.f};

  // prologue: X(0) -> buf0
  LOADX(0); WRITEX(0);

  int cur = 0;
  for (int kt = 0; kt < 12; ++kt) {
    __syncthreads();                     // A: prev COMPUTE done (W buf free); X[cur] visible
    STAGEW(kt);                          // DMA W(kt) into single W buffer
    if (kt < 11) LOADX(kt + 1);          // x fp32 loads fly concurrently with W DMA
    __syncthreads();                     // B: vmcnt drained -> W(kt) + x regs ready
    #pragma unroll
    for (int ks = 0; ks < 2; ++ks) {
      const int g = ks * 4 + quad;
      bf16x8 a[2];
      #pragma unroll
      for (int m = 0; m < 2; ++m) {
        const int ar = wr * 32 + 16 * m + col16;
        a[m] = *reinterpret_cast<const bf16x8*>(&XL(cur, ar * 64 + ((g ^ (ar & 7)) << 3)));
      }
      #pragma unroll
      for (int n = 0; n < 3; ++n) {
        const int br = wc * 48 + 16 * n + col16;
        const bf16x8 b = *reinterpret_cast<const bf16x8*>(&WL(br * 64 + ((g ^ (br & 7)) << 3)));
        #pragma unroll
        for (int m = 0; m < 2; ++m)
          acc[m][n] = __builtin_amdgcn_mfma_f32_16x16x32_bf16(a[m], b, acc[m][n], 0, 0, 0);
      }
    }
    if (kt < 11) WRITEX(cur ^ 1);        // X(kt+1) -> other buffer
    cur ^= 1;
  }

  // ---- epilogue: stage full 64x192 bf16 tile in LDS, then coalesced uint4 stores ----
  __syncthreads();                       // all MFMA LDS reads done; SM reusable
  #pragma unroll
  for (int n = 0; n < 3; ++n) {
    const int c = wc * 48 + 16 * n + col16;
    #pragma unroll
    for (int m = 0; m < 2; ++m) {
      #pragma unroll
      for (int i = 0; i < 4; ++i) {
        const int row = wr * 32 + 16 * m + quad * 4 + i;
        SM[row * OSTR + c] = f2bf(acc[m][n][i]);
      }
    }
  }
  __syncthreads();

  {
    const int t  = tid >> 3;             // 0..63
    const int g  = tid & 7;              // 16B chunk
    // q: linear rows
    const uint4 vq = *reinterpret_cast<const uint4*>(&SM[t * OSTR + g * 8]);
    *reinterpret_cast<uint4*>(&qo[(size_t)(m0 + t) * HEAD + g * 8]) = vq;
    // k: stored chunk g holds logical h-group g^(t&7)
    const uint4 vk = *reinterpret_cast<const uint4*>(&SM[t * OSTR + 64 + ((g ^ (t & 7)) << 3)]);
    *reinterpret_cast<uint4*>(&ko[(size_t)(m0 + t) * HEAD + g * 8]) = vk;
    // vT: row h = t, stored t-group g holds logical t-group g^(h&7); column-gather from LDS
    const int h  = t;
    const int gt = g ^ (h & 7);
    union { ushort us[8]; uint4 u; } pv;
    #pragma unroll
    for (int e = 0; e < 8; ++e)
      pv.us[e] = SM[(gt * 8 + e) * OSTR + 128 + h];
    const int bb = m0 >> 10, tinb = m0 & 1023;
    *reinterpret_cast<uint4*>(&vo[((size_t)bb * HEAD + h) * SEQ + tinb + g * 8]) = pv.u;
  }
  #undef LOADX
  #undef WRITEX
  #undef STAGEW
  #undef XL
  #undef WL
}

// ---------------- Flash attention v9 (frozen from R13) ----------------
__global__ __launch_bounds__(256) void attn_kernel(
    const ushort* __restrict__ q, const ushort* __restrict__ k,
    const ushort* __restrict__ vT, float* __restrict__ out,
    float* __restrict__ po, float* __restrict__ pl)
{
  __shared__ ushort Kl[2][64 * 64];     // 16 KB
  __shared__ ushort Vl[2][64 * 64];     // 16 KB
  __shared__ ushort lp[4][16][72];      // 9 KB per-wave P

  const int tid  = threadIdx.x;
  const int wave = tid >> 6, lane = tid & 63;
  const int bid  = blockIdx.x;
  const int b    = bid & 15;
  const int u    = bid >> 4;            // unit 0..43

  int j, s, ns;
  if (u < 4)       { j = u;                s = 0;           ns = 1; }
  else if (u < 12) { j = 4 + ((u - 4) >> 1);  s = (u - 4) & 1; ns = 2; }
  else             { j = 8 + ((u - 12) >> 2); s = (u - 12) & 3; ns = 4; }

  const int qt0 = j * 64;
  const int nt  = j + 1;
  const int t0  = (nt * s) / ns;
  const int t1  = (nt * (s + 1)) / ns;
  const float SC2 = 0.03608439182435161f * 1.4426950408889634f;  // 768^-0.5 * log2e

  const int col  = lane & 15;
  const int quad = lane >> 4;
  const int koff = quad * 8;

  const size_t qb = ((size_t)b * SEQ + qt0 + 16 * wave + col) * HEAD;
  const bf16x8 qa0 = *reinterpret_cast<const bf16x8*>(&q[qb + koff]);
  const bf16x8 qa1 = *reinterpret_cast<const bf16x8*>(&q[qb + koff + 32]);

  #define STAGE(t_, buf_) {                                                     \
    _Pragma("unroll")                                                           \
    for (int r = 0; r < 2; ++r)                                                 \
      lds_dma16(&k[((size_t)b * SEQ + (t_) * 64 + r * 32 + wave * 8 + (lane >> 3)) * HEAD + (lane & 7) * 8], \
                &Kl[buf_][(r * 32 + wave * 8) * 64]);                           \
    _Pragma("unroll")                                                           \
    for (int r = 0; r < 2; ++r)                                                 \
      lds_dma16(&vT[((size_t)b * HEAD + r * 32 + wave * 8 + (lane >> 3)) * SEQ + (t_) * 64 + (lane & 7) * 8], \
                &Vl[buf_][(r * 32 + wave * 8) * 64]);                           \
  }

  f32x4 o[4];
  #pragma unroll
  for (int hf = 0; hf < 4; ++hf) o[hf] = (f32x4){0.f, 0.f, 0.f, 0.f};
  float l_part[4];
  #pragma unroll
  for (int i = 0; i < 4; ++i) l_part[i] = 0.f;

  STAGE(t0, 0);

  for (int t = t0; t < t1; ++t) {
    const int cur = (t - t0) & 1;
    __syncthreads();                      // DMA of buf[cur] done; prev compute done
    if (t + 1 < t1) STAGE(t + 1, cur ^ 1);

    f32x4 sreg[4];
    #pragma unroll
    for (int f = 0; f < 4; ++f) {
      const int rowf = 16 * f + col;
      const bf16x8 kb0 = *reinterpret_cast<const bf16x8*>(
          &Kl[cur][rowf * 64 + ((quad ^ (rowf & 7)) << 3)]);
      const bf16x8 kb1 = *reinterpret_cast<const bf16x8*>(
          &Kl[cur][rowf * 64 + (((quad + 4) ^ (rowf & 7)) << 3)]);
      f32x4 z = (f32x4){0.f, 0.f, 0.f, 0.f};
      z       = __builtin_amdgcn_mfma_f32_16x16x32_bf16(qa0, kb0, z, 0, 0, 0);
      sreg[f] = __builtin_amdgcn_mfma_f32_16x16x32_bf16(qa1, kb1, z, 0, 0, 0);
    }

    const bool last = (t == nt - 1);
    #pragma unroll
    for (int f = 0; f < 4; ++f) {
      const int kvc = t * 64 + 16 * f + col;
      #pragma unroll
      for (int i = 0; i < 4; ++i) {
        float v = sreg[f][i];
        if (last && kvc > qt0 + 16 * wave + quad * 4 + i) v = -1e30f;
        const float p = exp2f(v * SC2);
        l_part[i] += p;
        lp[wave][quad * 4 + i][16 * f + col] = f2bf(p);
      }
    }

    #pragma unroll
    for (int ks = 0; ks < 2; ++ks) {
      const bf16x8 pa = *reinterpret_cast<const bf16x8*>(&lp[wave][col][ks * 32 + koff]);
      #pragma unroll
      for (int hf = 0; hf < 4; ++hf) {
        const int vrow = 16 * hf + col;
        const int g = ks * 4 + quad;
        const bf16x8 vb = *reinterpret_cast<const bf16x8*>(
            &Vl[cur][vrow * 64 + ((g ^ (vrow & 7)) << 3)]);
        o[hf] = __builtin_amdgcn_mfma_f32_16x16x32_bf16(pa, vb, o[hf], 0, 0, 0);
      }
    }
  }

  #pragma unroll
  for (int i = 0; i < 4; ++i) {
    #pragma unroll
    for (int d = 1; d < 16; d <<= 1) l_part[i] += __shfl_xor(l_part[i], d);
  }

  if (ns == 1) {
    #pragma unroll
    for (int i = 0; i < 4; ++i) {
      const float inv = 1.0f / l_part[i];
      const int tq = qt0 + 16 * wave + quad * 4 + i;
      #pragma unroll
      for (int hf = 0; hf < 4; ++hf)
        out[((size_t)b * SEQ + tq) * HEAD + 16 * hf + col] = o[hf][i] * inv;
    }
  } else {
    const int su = u - 4;                         // 0..39
    const int pidx = b * 40 + su;
    float* pob = &po[(size_t)pidx * 4096];
    #pragma unroll
    for (int i = 0; i < 4; ++i) {
      const int r = 16 * wave + quad * 4 + i;
      #pragma unroll
      for (int hf = 0; hf < 4; ++hf)
        pob[r * 64 + 16 * hf + col] = o[hf][i];
      if (col == 0) pl[pidx * 64 + r] = l_part[i];
    }
  }
  #undef STAGE
}

// ---------------- combine (frozen) ----------------
__global__ __launch_bounds__(256) void combine_kernel(
    const float* __restrict__ po, const float* __restrict__ pl,
    float* __restrict__ out)
{
  const int idx = blockIdx.x * 256 + threadIdx.x;   // 786432
  const int c = idx & 63;
  const int r = (idx >> 6) & 63;
  const int e = idx >> 12;                // 0..191
  const int jj = e % 12, b = e / 12;
  const int j = 4 + jj;
  const int su0 = (j < 8) ? (j - 4) * 2 : 8 + (j - 8) * 4;
  const int ns  = (j < 8) ? 2 : 4;
  float num = 0.f, den = 0.f;
  for (int s = 0; s < ns; ++s) {
    const int pidx = b * 40 + su0 + s;
    num += po[(size_t)pidx * 4096 + r * 64 + c];
    den += pl[pidx * 64 + r];
  }
  out[((size_t)b * SEQ + j * 64 + r) * HEAD + c] = num / den;
}

extern "C" void kernel_launch(void* const* d_in, const int* in_sizes, int n_in,
                              void* d_out, int out_size, void* d_ws, size_t ws_size,
                              hipStream_t stream) {
  const float* x  = (const float*)d_in[0];
  const float* Wq = (const float*)d_in[1];
  const float* Wk = (const float*)d_in[2];
  const float* Wv = (const float*)d_in[3];

  char* base = (char*)d_ws;
  ushort* qw  = (ushort*)(base);                        // [NT][64] bf16 linear   (2 MB)
  ushort* kw  = (ushort*)(base + (2u << 20));           // [NT][64] bf16 swizzled (2 MB)
  ushort* vTw = (ushort*)(base + (4u << 20));           // [B][64][1024] swizzled (2 MB)
  ushort* wtw = (ushort*)(base + (6u << 20));           // [192][768] swizzled    (288 KB)
  float*  po  = (float*) (base + (8u << 20));           // [16][40][4096] fp32    (10.5 MB)
  float*  pl  = (float*) (base + (20u << 20));          // [16][40][64] fp32      (164 KB)
  float*  out = (float*)d_out;

  convw_kernel<<<NQKV / 8, 256, 0, stream>>>(Wq, Wk, Wv, wtw);
  proj_kernel<<<NT / 64, 512, 0, stream>>>(x, wtw, qw, kw, vTw);
  attn_kernel<<<BATCH * 44, 256, 0, stream>>>(qw, kw, vTw, out, po, pl);
  combine_kernel<<<786432 / 256, 256, 0, stream>>>(po, pl, out);
}

// Round 26
// 39.977 us; speedup vs baseline: 1.1931x; 1.1931x over previous
//
#include <hip/hip_runtime.h>
#include <hip/hip_bf16.h>

typedef __attribute__((ext_vector_type(8))) short bf16x8;
typedef __attribute__((ext_vector_type(4))) float f32x4;

#define BATCH 16
#define SEQ   1024
#define EMB   768
#define HEAD  64
#define NT    (BATCH*SEQ)
#define NQKV  192
#define OSTR  200        // epilogue LDS tile stride (ushorts)

__device__ inline ushort f2bf(float f) {
  __hip_bfloat16 h = __float2bfloat16(f);
  return *reinterpret_cast<const ushort*>(&h);
}

__device__ inline void lds_dma16(const void* g, void* l) {
  __builtin_amdgcn_global_load_lds(
      (const __attribute__((address_space(1))) void*)g,
      (__attribute__((address_space(3))) void*)l, 16, 0, 0);
}

// ---------- W fp32 -> wt bf16 (pre-swizzled rows: chunk g stored at g^(row&7)) ----------
__global__ __launch_bounds__(256) void convw_kernel(
    const float* __restrict__ Wq, const float* __restrict__ Wk,
    const float* __restrict__ Wv, ushort* __restrict__ wt)
{
  const int row = blockIdx.x * 8 + (threadIdx.x >> 5);
  const float* W = (row < 64) ? Wq : (row < 128 ? Wk : Wv);
  const int r = row & 63;
  #pragma unroll
  for (int j = 0; j < 3; ++j) {
    const int c = (threadIdx.x & 31) + 32 * j;   // stored chunk 0..95
    const int grp = c >> 3, gst = c & 7;
    const int glog = gst ^ (row & 7);
    const int srccol = (grp << 6) + (glog << 3);
    const float4 f0 = *reinterpret_cast<const float4*>(&W[(size_t)r * EMB + srccol]);
    const float4 f1 = *reinterpret_cast<const float4*>(&W[(size_t)r * EMB + srccol + 4]);
    union { ushort us[8]; uint4 u; } o;
    o.us[0]=f2bf(f0.x); o.us[1]=f2bf(f0.y); o.us[2]=f2bf(f0.z); o.us[3]=f2bf(f0.w);
    o.us[4]=f2bf(f1.x); o.us[5]=f2bf(f1.y); o.us[6]=f2bf(f1.z); o.us[7]=f2bf(f1.w);
    *reinterpret_cast<uint4*>(&wt[(size_t)row * EMB + (c << 3)]) = o.u;
  }
}

// ---------- proj v5b: R15 main loop + 2-phase-deep x register prefetch ----------
// grid 256 x 512 thr. Block: M=64, N=192, BK=64. All global stores are uint4.
__global__ __launch_bounds__(512, 4) void proj_kernel(
    const float* __restrict__ x, const ushort* __restrict__ wt,
    ushort* __restrict__ qo, ushort* __restrict__ ko, ushort* __restrict__ vo)
{
  __shared__ ushort SM[32768];   // 64 KB: [Xl 2x4096 | Wl 2x12288]; epilogue reuses as Ol[64][OSTR]

  const int tid  = threadIdx.x;
  const int wave = tid >> 6, lane = tid & 63;
  const int m0   = blockIdx.x * 64;
  const int wr   = wave >> 2, wc = wave & 3;
  const int col16 = lane & 15, quad = lane >> 4;

  const int xrow = tid >> 3;             // 0..63
  const int xc   = (tid & 7) * 8;        // float col
  const int xchk = tid & 7;              // 16B chunk idx

  #define XL(buf_, idx_) SM[(buf_) * 4096 + (idx_)]
  #define WL(buf_, idx_) SM[8192 + (buf_) * 12288 + (idx_)]

  #define LOADX2(kt_, A_, B_) {                                                 \
    const float* p = &x[(size_t)(m0 + xrow) * EMB + (kt_) * 64 + xc];           \
    A_ = *reinterpret_cast<const float4*>(p);                                   \
    B_ = *reinterpret_cast<const float4*>(p + 4); }

  #define WRITEX2(buf_, A_, B_) {                                               \
    union { ushort us[8]; uint4 u; } p;                                         \
    p.us[0]=f2bf((A_).x); p.us[1]=f2bf((A_).y); p.us[2]=f2bf((A_).z); p.us[3]=f2bf((A_).w); \
    p.us[4]=f2bf((B_).x); p.us[5]=f2bf((B_).y); p.us[6]=f2bf((B_).z); p.us[7]=f2bf((B_).w); \
    *reinterpret_cast<uint4*>(&XL(buf_, xrow * 64 + ((xchk ^ (xrow & 7)) << 3))) = p.u; }

  #define STAGEW(kt_, buf_) { _Pragma("unroll")                                 \
    for (int u = 0; u < 3; ++u) {                                               \
      lds_dma16(&wt[(size_t)(u * 64 + (tid >> 3)) * EMB + (kt_) * 64 + (tid & 7) * 8], \
                &WL(buf_, (u * 64 + wave * 8) * 64));                           \
    } }

  #define COMPUTE(buf_) { _Pragma("unroll")                                     \
    for (int ks = 0; ks < 2; ++ks) {                                            \
      const int g = ks * 4 + quad;                                              \
      bf16x8 a[2];                                                              \
      _Pragma("unroll")                                                         \
      for (int m = 0; m < 2; ++m) {                                             \
        const int ar = wr * 32 + 16 * m + col16;                                \
        a[m] = *reinterpret_cast<const bf16x8*>(&XL(buf_, ar * 64 + ((g ^ (ar & 7)) << 3))); \
      }                                                                         \
      _Pragma("unroll")                                                         \
      for (int n = 0; n < 3; ++n) {                                             \
        const int br = wc * 48 + 16 * n + col16;                                \
        const bf16x8 b = *reinterpret_cast<const bf16x8*>(&WL(buf_, br * 64 + ((g ^ (br & 7)) << 3))); \
        _Pragma("unroll")                                                       \
        for (int m = 0; m < 2; ++m)                                             \
          acc[m][n] = __builtin_amdgcn_mfma_f32_16x16x32_bf16(a[m], b, acc[m][n], 0, 0, 0); \
      }                                                                         \
    } }

  f32x4 acc[2][3];
  #pragma unroll
  for (int m = 0; m < 2; ++m)
    #pragma unroll
    for (int n = 0; n < 3; ++n) acc[m][n] = (f32x4){0.f, 0.f, 0.f, 0.f};

  float4 xa0, xb0, xa1, xb1;

  // prologue: buf0 <- X(0),W(0); set1 <- X(1)
  LOADX2(0, xa0, xb0);
  WRITEX2(0, xa0, xb0);
  STAGEW(0, 0);
  LOADX2(1, xa1, xb1);

  #pragma unroll
  for (int kt = 0; kt < 12; kt += 2) {
    // ---- phase kt (buf0) ----
    __syncthreads();                       // buf0 ready (vmcnt+lgkm drained)
    if (kt < 10) LOADX2(kt + 2, xa0, xb0); // x first: cold HBM, 2-phase window
    if (kt < 11) STAGEW(kt + 1, 1);
    COMPUTE(0);
    if (kt < 11) WRITEX2(1, xa1, xb1);     // X(kt+1) -> buf1
    // ---- phase kt+1 (buf1) ----
    __syncthreads();                       // buf1 ready
    if (kt + 1 < 10) LOADX2(kt + 3, xa1, xb1);
    if (kt + 1 < 11) STAGEW(kt + 2, 0);
    COMPUTE(1);
    if (kt + 1 < 11) WRITEX2(0, xa0, xb0); // X(kt+2) -> buf0
  }

  // ---- epilogue: stage full 64x192 bf16 tile in LDS, then coalesced uint4 stores ----
  __syncthreads();                         // all MFMA LDS reads done; SM reusable
  #pragma unroll
  for (int n = 0; n < 3; ++n) {
    const int c = wc * 48 + 16 * n + col16;
    #pragma unroll
    for (int m = 0; m < 2; ++m) {
      #pragma unroll
      for (int i = 0; i < 4; ++i) {
        const int row = wr * 32 + 16 * m + quad * 4 + i;
        SM[row * OSTR + c] = f2bf(acc[m][n][i]);
      }
    }
  }
  __syncthreads();

  {
    const int t  = tid >> 3;               // 0..63
    const int g  = tid & 7;                // 16B chunk
    // q: linear rows
    const uint4 vq = *reinterpret_cast<const uint4*>(&SM[t * OSTR + g * 8]);
    *reinterpret_cast<uint4*>(&qo[(size_t)(m0 + t) * HEAD + g * 8]) = vq;
    // k: stored chunk g holds logical h-group g^(t&7)
    const uint4 vk = *reinterpret_cast<const uint4*>(&SM[t * OSTR + 64 + ((g ^ (t & 7)) << 3)]);
    *reinterpret_cast<uint4*>(&ko[(size_t)(m0 + t) * HEAD + g * 8]) = vk;
    // vT: row h = t, stored t-group g holds logical t-group g^(h&7); column-gather from LDS
    const int h  = t;
    const int gt = g ^ (h & 7);
    union { ushort us[8]; uint4 u; } pv;
    #pragma unroll
    for (int e = 0; e < 8; ++e)
      pv.us[e] = SM[(gt * 8 + e) * OSTR + 128 + h];
    const int bb = m0 >> 10, tinb = m0 & 1023;
    *reinterpret_cast<uint4*>(&vo[((size_t)bb * HEAD + h) * SEQ + tinb + g * 8]) = pv.u;
  }
  #undef LOADX2
  #undef WRITEX2
  #undef STAGEW
  #undef COMPUTE
  #undef XL
  #undef WL
}

// ---------------- Flash attention v9 (frozen from R13) ----------------
__global__ __launch_bounds__(256) void attn_kernel(
    const ushort* __restrict__ q, const ushort* __restrict__ k,
    const ushort* __restrict__ vT, float* __restrict__ out,
    float* __restrict__ po, float* __restrict__ pl)
{
  __shared__ ushort Kl[2][64 * 64];     // 16 KB
  __shared__ ushort Vl[2][64 * 64];     // 16 KB
  __shared__ ushort lp[4][16][72];      // 9 KB per-wave P

  const int tid  = threadIdx.x;
  const int wave = tid >> 6, lane = tid & 63;
  const int bid  = blockIdx.x;
  const int b    = bid & 15;
  const int u    = bid >> 4;            // unit 0..43

  int j, s, ns;
  if (u < 4)       { j = u;                s = 0;           ns = 1; }
  else if (u < 12) { j = 4 + ((u - 4) >> 1);  s = (u - 4) & 1; ns = 2; }
  else             { j = 8 + ((u - 12) >> 2); s = (u - 12) & 3; ns = 4; }

  const int qt0 = j * 64;
  const int nt  = j + 1;
  const int t0  = (nt * s) / ns;
  const int t1  = (nt * (s + 1)) / ns;
  const float SC2 = 0.03608439182435161f * 1.4426950408889634f;  // 768^-0.5 * log2e

  const int col  = lane & 15;
  const int quad = lane >> 4;
  const int koff = quad * 8;

  const size_t qb = ((size_t)b * SEQ + qt0 + 16 * wave + col) * HEAD;
  const bf16x8 qa0 = *reinterpret_cast<const bf16x8*>(&q[qb + koff]);
  const bf16x8 qa1 = *reinterpret_cast<const bf16x8*>(&q[qb + koff + 32]);

  #define STAGE(t_, buf_) {                                                     \
    _Pragma("unroll")                                                           \
    for (int r = 0; r < 2; ++r)                                                 \
      lds_dma16(&k[((size_t)b * SEQ + (t_) * 64 + r * 32 + wave * 8 + (lane >> 3)) * HEAD + (lane & 7) * 8], \
                &Kl[buf_][(r * 32 + wave * 8) * 64]);                           \
    _Pragma("unroll")                                                           \
    for (int r = 0; r < 2; ++r)                                                 \
      lds_dma16(&vT[((size_t)b * HEAD + r * 32 + wave * 8 + (lane >> 3)) * SEQ + (t_) * 64 + (lane & 7) * 8], \
                &Vl[buf_][(r * 32 + wave * 8) * 64]);                           \
  }

  f32x4 o[4];
  #pragma unroll
  for (int hf = 0; hf < 4; ++hf) o[hf] = (f32x4){0.f, 0.f, 0.f, 0.f};
  float l_part[4];
  #pragma unroll
  for (int i = 0; i < 4; ++i) l_part[i] = 0.f;

  STAGE(t0, 0);

  for (int t = t0; t < t1; ++t) {
    const int cur = (t - t0) & 1;
    __syncthreads();                      // DMA of buf[cur] done; prev compute done
    if (t + 1 < t1) STAGE(t + 1, cur ^ 1);

    f32x4 sreg[4];
    #pragma unroll
    for (int f = 0; f < 4; ++f) {
      const int rowf = 16 * f + col;
      const bf16x8 kb0 = *reinterpret_cast<const bf16x8*>(
          &Kl[cur][rowf * 64 + ((quad ^ (rowf & 7)) << 3)]);
      const bf16x8 kb1 = *reinterpret_cast<const bf16x8*>(
          &Kl[cur][rowf * 64 + (((quad + 4) ^ (rowf & 7)) << 3)]);
      f32x4 z = (f32x4){0.f, 0.f, 0.f, 0.f};
      z       = __builtin_amdgcn_mfma_f32_16x16x32_bf16(qa0, kb0, z, 0, 0, 0);
      sreg[f] = __builtin_amdgcn_mfma_f32_16x16x32_bf16(qa1, kb1, z, 0, 0, 0);
    }

    const bool last = (t == nt - 1);
    #pragma unroll
    for (int f = 0; f < 4; ++f) {
      const int kvc = t * 64 + 16 * f + col;
      #pragma unroll
      for (int i = 0; i < 4; ++i) {
        float v = sreg[f][i];
        if (last && kvc > qt0 + 16 * wave + quad * 4 + i) v = -1e30f;
        const float p = exp2f(v * SC2);
        l_part[i] += p;
        lp[wave][quad * 4 + i][16 * f + col] = f2bf(p);
      }
    }

    #pragma unroll
    for (int ks = 0; ks < 2; ++ks) {
      const bf16x8 pa = *reinterpret_cast<const bf16x8*>(&lp[wave][col][ks * 32 + koff]);
      #pragma unroll
      for (int hf = 0; hf < 4; ++hf) {
        const int vrow = 16 * hf + col;
        const int g = ks * 4 + quad;
        const bf16x8 vb = *reinterpret_cast<const bf16x8*>(
            &Vl[cur][vrow * 64 + ((g ^ (vrow & 7)) << 3)]);
        o[hf] = __builtin_amdgcn_mfma_f32_16x16x32_bf16(pa, vb, o[hf], 0, 0, 0);
      }
    }
  }

  #pragma unroll
  for (int i = 0; i < 4; ++i) {
    #pragma unroll
    for (int d = 1; d < 16; d <<= 1) l_part[i] += __shfl_xor(l_part[i], d);
  }

  if (ns == 1) {
    #pragma unroll
    for (int i = 0; i < 4; ++i) {
      const float inv = 1.0f / l_part[i];
      const int tq = qt0 + 16 * wave + quad * 4 + i;
      #pragma unroll
      for (int hf = 0; hf < 4; ++hf)
        out[((size_t)b * SEQ + tq) * HEAD + 16 * hf + col] = o[hf][i] * inv;
    }
  } else {
    const int su = u - 4;                         // 0..39
    const int pidx = b * 40 + su;
    float* pob = &po[(size_t)pidx * 4096];
    #pragma unroll
    for (int i = 0; i < 4; ++i) {
      const int r = 16 * wave + quad * 4 + i;
      #pragma unroll
      for (int hf = 0; hf < 4; ++hf)
        pob[r * 64 + 16 * hf + col] = o[hf][i];
      if (col == 0) pl[pidx * 64 + r] = l_part[i];
    }
  }
  #undef STAGE
}

// ---------------- combine (frozen) ----------------
__global__ __launch_bounds__(256) void combine_kernel(
    const float* __restrict__ po, const float* __restrict__ pl,
    float* __restrict__ out)
{
  const int idx = blockIdx.x * 256 + threadIdx.x;   // 786432
  const int c = idx & 63;
  const int r = (idx >> 6) & 63;
  const int e = idx >> 12;                // 0..191
  const int jj = e % 12, b = e / 12;
  const int j = 4 + jj;
  const int su0 = (j < 8) ? (j - 4) * 2 : 8 + (j - 8) * 4;
  const int ns  = (j < 8) ? 2 : 4;
  float num = 0.f, den = 0.f;
  for (int s = 0; s < ns; ++s) {
    const int pidx = b * 40 + su0 + s;
    num += po[(size_t)pidx * 4096 + r * 64 + c];
    den += pl[pidx * 64 + r];
  }
  out[((size_t)b * SEQ + j * 64 + r) * HEAD + c] = num / den;
}

extern "C" void kernel_launch(void* const* d_in, const int* in_sizes, int n_in,
                              void* d_out, int out_size, void* d_ws, size_t ws_size,
                              hipStream_t stream) {
  const float* x  = (const float*)d_in[0];
  const float* Wq = (const float*)d_in[1];
  const float* Wk = (const float*)d_in[2];
  const float* Wv = (const float*)d_in[3];

  char* base = (char*)d_ws;
  ushort* qw  = (ushort*)(base);                        // [NT][64] bf16 linear   (2 MB)
  ushort* kw  = (ushort*)(base + (2u << 20));           // [NT][64] bf16 swizzled (2 MB)
  ushort* vTw = (ushort*)(base + (4u << 20));           // [B][64][1024] swizzled (2 MB)
  ushort* wtw = (ushort*)(base + (6u << 20));           // [192][768] swizzled    (288 KB)
  float*  po  = (float*) (base + (8u << 20));           // [16][40][4096] fp32    (10.5 MB)
  float*  pl  = (float*) (base + (20u << 20));          // [16][40][64] fp32      (164 KB)
  float*  out = (float*)d_out;

  convw_kernel<<<NQKV / 8, 256, 0, stream>>>(Wq, Wk, Wv, wtw);
  proj_kernel<<<NT / 64, 512, 0, stream>>>(x, wtw, qw, kw, vTw);
  attn_kernel<<<BATCH * 44, 256, 0, stream>>>(qw, kw, vTw, out, po, pl);
  combine_kernel<<<786432 / 256, 256, 0, stream>>>(po, pl, out);
}